// Round 4
// baseline (405.426 us; speedup 1.0000x reference)
//
#include <hip/hip_runtime.h>

#define DD 256   // in_dim (= 2H)
#define HH 128   // per-branch out dim
#define CC 64    // n_class
#define BB 1024
#define SS1 25
#define SS2 10
#define NN 100000

typedef __attribute__((ext_vector_type(8))) short bf16x8;
typedef __attribute__((ext_vector_type(4))) float f32x4;

__device__ inline unsigned short f2b(float x) {
    union { float f; unsigned u; } v; v.f = x;
    unsigned r = (v.u + 0x7fffu + ((v.u >> 16) & 1u)) >> 16;
    return (unsigned short)r;
}
__device__ inline float b2f(unsigned u16) {
    union { unsigned u; float f; } v; v.u = u16 << 16;
    return v.f;
}

__device__ inline void async_load16(const void* g, void* l) {
    __builtin_amdgcn_global_load_lds(
        (const __attribute__((address_space(1))) void*)g,
        (__attribute__((address_space(3))) void*)l, 16, 0, 0);
}

// ---------------------------------------------------------------------------
// W prep: [Wx1 | Wn1] fp32 [256][128]x2 -> bf16, MFMA B-fragment order:
//   frag = kc*16 + nt  (kc<8, nt<16; nt<8 -> Wx cols, nt>=8 -> Wn cols)
//   Wsw[(frag*64 + lane)*8 + j] = Wcat[kc*32 + (lane>>4)*8 + j][nt*16 + (lane&15)]
// ---------------------------------------------------------------------------
__global__ __launch_bounds__(256)
void prep_w(const float* __restrict__ Wx, const float* __restrict__ Wn,
            unsigned short* __restrict__ Wsw) {
    const int t    = blockIdx.x * 256 + threadIdx.x;   // 0..8191
    const int lane = t & 63;
    const int frag = t >> 6;                           // kc*16 + nt
    const int kc = frag >> 4, nt = frag & 15;
    const int quad = lane >> 4, lr = lane & 15;
    unsigned short v[8];
#pragma unroll
    for (int j = 0; j < 8; ++j) {
        int k = kc * 32 + quad * 8 + j;
        int n = nt * 16 + lr;                          // 0..255
        float w = (n < HH) ? Wx[k * HH + n] : Wn[k * HH + (n - HH)];
        v[j] = f2b(w);
    }
    ((uint4*)Wsw)[t] = *(uint4*)v;
}

// ---------------------------------------------------------------------------
// PQ = feat @ [Wx1 | Wn1] -> bf16 [NN][256]
// BM=32, 256 thr (4 waves). Phases:
//  1) async DMA: 32 fp32 rows -> LDS (global_load_lds x16B, 8 rows/wave)
//  2) reg-staged convert fp32 -> bf16 (RNE) into A2 (in-place over dead af)
//  3) MFMA: wave w owns col-tiles w*4..w*4+3; 8 kc x 4 ntl x 2 rowgroups
//  4) epilogue: acc -> bf16 into disjoint LDS region O, then coalesced stores
// LDS 33.8 KB -> 4 blocks/CU; __launch_bounds__(256,4) caps VGPR at 128.
// ---------------------------------------------------------------------------
__global__ __launch_bounds__(256, 4)
void pq_gemm(const float* __restrict__ feat,
             const unsigned short* __restrict__ Wsw,
             unsigned short* __restrict__ PQb) {
    constexpr int RSF = 260;   // fp32 row stride (dword bank step 4 -> 2-way)
    constexpr int RSB = 264;   // bf16 row stride (528B, 16B aligned)
    __shared__ union {
        float af[32 * RSF];            // 33280 B
        unsigned short ab[2 * 32 * RSB];  // 33792 B  [0..]: A2, [32*RSB..]: O
    } sm;
    unsigned short* const A2 = sm.ab;
    unsigned short* const O  = sm.ab + 32 * RSB;

    const int r0 = blockIdx.x * 32;
    const int t  = threadIdx.x;
    const int wv = t >> 6, lane = t & 63;

    // ---- 1) async stage: rows wv*8..wv*8+7, 1 KB each, lane offset implicit
#pragma unroll
    for (int i = 0; i < 8; ++i) {
        int row = wv * 8 + i;
        const float* g = feat + (long)(r0 + row) * DD + lane * 4;
        async_load16(g, &sm.af[row * RSF]);
    }
    __syncthreads();

    // ---- 2) convert: thread owns (row = t>>3, seg = t&7) -> 32 floats
    const int crow = t >> 3, cseg = t & 7;
    float4 v[8];
#pragma unroll
    for (int i = 0; i < 8; ++i) {
        int ii = (i + cseg) & 7;                    // bank stagger
        v[ii] = *(float4*)&sm.af[crow * RSF + cseg * 32 + ii * 4];
    }
    __syncthreads();
    unsigned dw[16];
#pragma unroll
    for (int i = 0; i < 8; ++i) {
        dw[2 * i]     = (unsigned)f2b(v[i].x) | ((unsigned)f2b(v[i].y) << 16);
        dw[2 * i + 1] = (unsigned)f2b(v[i].z) | ((unsigned)f2b(v[i].w) << 16);
    }
#pragma unroll
    for (int q = 0; q < 4; ++q) {
        int qq = (q + crow) & 3;                    // bank stagger
        *(uint4*)&A2[crow * RSB + cseg * 32 + qq * 8] = *(uint4*)&dw[qq * 4];
    }
    __syncthreads();

    // ---- 3) MFMA: wave wv -> col tiles wv*4..wv*4+3 (64 cols), 32 rows
    const int quad = lane >> 4, lr = lane & 15;
    f32x4 acc[2][4] = {};
#pragma unroll
    for (int kc = 0; kc < 8; ++kc) {
        bf16x8 a0 = *(const bf16x8*)&A2[(lr)      * RSB + kc * 32 + quad * 8];
        bf16x8 a1 = *(const bf16x8*)&A2[(16 + lr) * RSB + kc * 32 + quad * 8];
#pragma unroll
        for (int ntl = 0; ntl < 4; ++ntl) {
            bf16x8 b = *(const bf16x8*)&Wsw[((kc * 16 + wv * 4 + ntl) * 64 + lane) * 8];
            acc[0][ntl] = __builtin_amdgcn_mfma_f32_16x16x32_bf16(a0, b, acc[0][ntl], 0, 0, 0);
            acc[1][ntl] = __builtin_amdgcn_mfma_f32_16x16x32_bf16(a1, b, acc[1][ntl], 0, 0, 0);
        }
    }

    // ---- 4) epilogue: C/D row=quad*4+r, col=lr; write bf16 into O (disjoint)
#pragma unroll
    for (int rg = 0; rg < 2; ++rg)
#pragma unroll
        for (int ntl = 0; ntl < 4; ++ntl) {
            int col = (wv * 4 + ntl) * 16 + lr;
#pragma unroll
            for (int r = 0; r < 4; ++r)
                O[(rg * 16 + quad * 4 + r) * RSB + col] = f2b(acc[rg][ntl][r]);
        }
    __syncthreads();

    // readback + coalesced 16B stores (thread owns row=t>>3, seg=t&7)
#pragma unroll
    for (int q = 0; q < 4; ++q) {
        int qq = (q + crow) & 3;
        uint4 d = *(uint4*)&O[crow * RSB + cseg * 32 + qq * 8];
        *(uint4*)&PQb[(long)(r0 + crow) * DD + cseg * 32 + qq * 8] = d;
    }
}

// ---------------------------------------------------------------------------
// build_g1: g1b[row] = bf16(relu([PQ[ids1[row]].X + bx1 | mean_j PQ[ids2].N + bn1]))
// 2 rows per wave (half-wave each, 8 B/lane); 10 neighbor ids via shfl.
// ---------------------------------------------------------------------------
__global__ __launch_bounds__(256)
void build_g1(const unsigned short* __restrict__ PQb,
              const int* __restrict__ ids1, const int* __restrict__ ids2,
              const float* __restrict__ bx1, const float* __restrict__ bn1,
              unsigned short* __restrict__ g1b) {
    const int wv   = threadIdx.x >> 6;
    const int lane = threadIdx.x & 63;
    const int sub  = lane >> 5, lr = lane & 31;
    const int row  = blockIdx.x * 8 + wv * 2 + sub;

    long xr = (long)ids1[row];
    uint2 xv = *(const uint2*)&PQb[xr * DD + lr * 4];

    int myid = ids2[row * SS2 + (lr % SS2)];
    float4 acc = {0.f, 0.f, 0.f, 0.f};
#pragma unroll
    for (int j = 0; j < SS2; ++j) {
        long nr = (long)__shfl(myid, (lane & 32) + j);
        uint2 nv = *(const uint2*)&PQb[nr * DD + HH + lr * 4];
        acc.x += b2f(nv.x & 0xffff); acc.y += b2f(nv.x >> 16);
        acc.z += b2f(nv.y & 0xffff); acc.w += b2f(nv.y >> 16);
    }
    float4 bx = *(const float4*)&bx1[lr * 4];
    float4 bn = *(const float4*)&bn1[lr * 4];
    float x0 = fmaxf(b2f(xv.x & 0xffff) + bx.x, 0.f);
    float x1 = fmaxf(b2f(xv.x >> 16)    + bx.y, 0.f);
    float x2 = fmaxf(b2f(xv.y & 0xffff) + bx.z, 0.f);
    float x3 = fmaxf(b2f(xv.y >> 16)    + bx.w, 0.f);
    constexpr float inv = 1.f / SS2;
    float n0 = fmaxf(acc.x * inv + bn.x, 0.f);
    float n1 = fmaxf(acc.y * inv + bn.y, 0.f);
    float n2 = fmaxf(acc.z * inv + bn.z, 0.f);
    float n3 = fmaxf(acc.w * inv + bn.w, 0.f);

    uint2 ox = { (unsigned)f2b(x0) | ((unsigned)f2b(x1) << 16),
                 (unsigned)f2b(x2) | ((unsigned)f2b(x3) << 16) };
    uint2 on = { (unsigned)f2b(n0) | ((unsigned)f2b(n1) << 16),
                 (unsigned)f2b(n2) | ((unsigned)f2b(n3) << 16) };
    *(uint2*)&g1b[(long)row * DD + lr * 4]      = ox;
    *(uint2*)&g1b[(long)row * DD + HH + lr * 4] = on;
}

// ---------------------------------------------------------------------------
// build_g0: g0[row] = relu([PQ[ids0[row]].X + bx1 | mean_{j<25} PQ[ids1].N + bn1])
// fp32 output; 2 rows per wave.
// ---------------------------------------------------------------------------
__global__ __launch_bounds__(256)
void build_g0(const unsigned short* __restrict__ PQb,
              const int* __restrict__ ids0, const int* __restrict__ ids1,
              const float* __restrict__ bx1, const float* __restrict__ bn1,
              float* __restrict__ g0) {
    const int wv   = threadIdx.x >> 6;
    const int lane = threadIdx.x & 63;
    const int sub  = lane >> 5, lr = lane & 31;
    const int row  = blockIdx.x * 8 + wv * 2 + sub;

    long xr = (long)ids0[row];
    uint2 xv = *(const uint2*)&PQb[xr * DD + lr * 4];

    int myid = ids1[row * SS1 + (lr % SS1)];
    float4 acc = {0.f, 0.f, 0.f, 0.f};
#pragma unroll 5
    for (int j = 0; j < SS1; ++j) {
        long nr = (long)__shfl(myid, (lane & 32) + j);
        uint2 nv = *(const uint2*)&PQb[nr * DD + HH + lr * 4];
        acc.x += b2f(nv.x & 0xffff); acc.y += b2f(nv.x >> 16);
        acc.z += b2f(nv.y & 0xffff); acc.w += b2f(nv.y >> 16);
    }
    float4 bx = *(const float4*)&bx1[lr * 4];
    float4 bn = *(const float4*)&bn1[lr * 4];
    constexpr float inv = 1.f / SS1;
    float4 xo = { fmaxf(b2f(xv.x & 0xffff) + bx.x, 0.f),
                  fmaxf(b2f(xv.x >> 16)    + bx.y, 0.f),
                  fmaxf(b2f(xv.y & 0xffff) + bx.z, 0.f),
                  fmaxf(b2f(xv.y >> 16)    + bx.w, 0.f) };
    float4 no = { fmaxf(acc.x * inv + bn.x, 0.f),
                  fmaxf(acc.y * inv + bn.y, 0.f),
                  fmaxf(acc.z * inv + bn.z, 0.f),
                  fmaxf(acc.w * inv + bn.w, 0.f) };
    *(float4*)&g0[(long)row * DD + lr * 4]      = xo;
    *(float4*)&g0[(long)row * DD + HH + lr * 4] = no;
}

// ---------------------------------------------------------------------------
// agg2 (layer 2, identity act, gm-mean fused):
//   f0[i] = [ g0[i].Wx2 + bx2 | (mean_{j<25} g1b[i*25+j]) . Wn2 + bn2 ]
// ---------------------------------------------------------------------------
__global__ __launch_bounds__(256)
void agg2(const float* __restrict__ g0, const unsigned short* __restrict__ g1b,
          const float* __restrict__ Wx, const float* __restrict__ bx,
          const float* __restrict__ Wn, const float* __restrict__ bn,
          float* __restrict__ f0) {
    constexpr int RT = 16;
    __shared__ float aX[RT][DD];
    __shared__ float aN[RT][DD];
    const int r0 = blockIdx.x * RT;
    const int t  = threadIdx.x;

#pragma unroll
    for (int i = 0; i < 4; ++i) {
        int id = i * 256 + t;
        int r = id >> 6, c4 = (id & 63) * 4;
        *(float4*)&aX[r][c4] = *(const float4*)(g0 + (long)(r0 + r) * DD + c4);
        float4 acc = {0.f, 0.f, 0.f, 0.f};
        const unsigned short* base = g1b + ((long)(r0 + r) * SS1) * DD + c4;
        for (int j = 0; j < SS1; ++j) {
            ushort4 u = *(const ushort4*)(base + (long)j * DD);
            acc.x += b2f(u.x); acc.y += b2f(u.y);
            acc.z += b2f(u.z); acc.w += b2f(u.w);
        }
        acc.x *= (1.f / SS1); acc.y *= (1.f / SS1);
        acc.z *= (1.f / SS1); acc.w *= (1.f / SS1);
        *(float4*)&aN[r][c4] = acc;
    }
    __syncthreads();

    const bool xhalf = (t < HH);
    const float* __restrict__ W = xhalf ? Wx : Wn;
    const float (* __restrict__ A)[DD] = xhalf ? aX : aN;
    const int c = t & (HH - 1);

    float acc[RT];
#pragma unroll
    for (int r = 0; r < RT; ++r) acc[r] = 0.f;
#pragma unroll 4
    for (int k = 0; k < DD; ++k) {
        float wv = W[k * HH + c];
#pragma unroll
        for (int r = 0; r < RT; ++r) acc[r] += A[r][k] * wv;
    }
    const float bias = xhalf ? bx[c] : bn[c];
#pragma unroll
    for (int r = 0; r < RT; ++r)
        f0[(long)(r0 + r) * DD + t] = acc[r] + bias;
}

// ---------------------------------------------------------------------------
// head: out[1024][64] = f0 @ Wfc + bfc
// ---------------------------------------------------------------------------
__global__ __launch_bounds__(256)
void head_kernel(const float* __restrict__ f0, const float* __restrict__ Wfc,
                 const float* __restrict__ bfc, float* __restrict__ out) {
    constexpr int RT = 16;
    __shared__ float aX[64][DD];
    const int r0 = blockIdx.x * 64;
    const int t  = threadIdx.x;

    for (int basei = 0; basei < 64 * DD; basei += 1024) {
        int idx = basei + t * 4;
        int r = idx >> 8, k = idx & 255;
        *(float4*)&aX[r][k] = *(const float4*)(f0 + (long)(r0 + r) * DD + k);
    }
    __syncthreads();

    const int c  = t & (CC - 1);
    const int rg = t >> 6;
    float acc[RT];
#pragma unroll
    for (int r = 0; r < RT; ++r) acc[r] = 0.f;
#pragma unroll 4
    for (int k = 0; k < DD; ++k) {
        float wv = Wfc[k * CC + c];
#pragma unroll
        for (int r = 0; r < RT; ++r) acc[r] += aX[rg * RT + r][k] * wv;
    }
    const float bias = bfc[c];
#pragma unroll
    for (int r = 0; r < RT; ++r)
        out[(long)(r0 + rg * RT + r) * CC + c] = acc[r] + bias;
}

// ---------------------------------------------------------------------------
extern "C" void kernel_launch(void* const* d_in, const int* in_sizes, int n_in,
                              void* d_out, int out_size, void* d_ws, size_t ws_size,
                              hipStream_t stream) {
    const int*   ids0 = (const int*)d_in[0];
    const int*   ids1 = (const int*)d_in[1];
    const int*   ids2 = (const int*)d_in[2];
    const float* feat = (const float*)d_in[3];
    const float* Wx1  = (const float*)d_in[4];
    const float* bx1  = (const float*)d_in[5];
    const float* Wn1  = (const float*)d_in[6];
    const float* bn1  = (const float*)d_in[7];
    const float* Wx2  = (const float*)d_in[8];
    const float* bx2  = (const float*)d_in[9];
    const float* Wn2  = (const float*)d_in[10];
    const float* bn2  = (const float*)d_in[11];
    const float* Wfc  = (const float*)d_in[12];
    const float* bfc  = (const float*)d_in[13];
    float* out = (float*)d_out;

    const long M1 = (long)BB * SS1;                      // 25600
    float* wsf = (float*)d_ws;
    float* g0 = wsf;  wsf += (long)BB * DD;              // 1 MB
    float* f0 = wsf;  wsf += (long)BB * DD;              // 1 MB
    unsigned short* PQb = (unsigned short*)wsf;          // 51.2 MB
    unsigned short* g1b = PQb + (long)NN * DD;           // 13.1 MB
    unsigned short* Wsw = g1b + M1 * DD;                 // 128 KB

    // 1) W prep (bf16 + B-fragment swizzle of [Wx1|Wn1])
    prep_w<<<32, 256, 0, stream>>>(Wx1, Wn1, Wsw);
    // 2) PQ = feat @ [Wx1|Wn1]  (bf16)                  [100000,256]
    pq_gemm<<<NN / 32, 256, 0, stream>>>(feat, Wsw, PQb);
    // 3) g1 (bf16)                                      [25600,256]
    build_g1<<<M1 / 8, 256, 0, stream>>>(PQb, ids1, ids2, bx1, bn1, g1b);
    // 4) g0 (fp32)                                      [1024,256]
    build_g0<<<BB / 8, 256, 0, stream>>>(PQb, ids0, ids1, bx1, bn1, g0);
    // 5) f0 = [g0.Wx2 | mean(g1).Wn2] (gm fused)        [1024,256]
    agg2<<<BB / 16, 256, 0, stream>>>(g0, g1b, Wx2, bx2, Wn2, bn2, f0);
    // 6) out = f0 @ Wfc + bfc                           [1024,64]
    head_kernel<<<BB / 64, 256, 0, stream>>>(f0, Wfc, bfc, out);
}

// Round 5
// 385.595 us; speedup vs baseline: 1.0514x; 1.0514x over previous
//
#include <hip/hip_runtime.h>

#define DD 256   // in_dim (= 2H)
#define HH 128   // per-branch out dim
#define CC 64    // n_class
#define BB 1024
#define SS1 25
#define SS2 10
#define NN 100000

typedef __attribute__((ext_vector_type(8))) short bf16x8;
typedef __attribute__((ext_vector_type(4))) float f32x4;

__device__ inline unsigned short f2b(float x) {
    union { float f; unsigned u; } v; v.f = x;
    unsigned r = (v.u + 0x7fffu + ((v.u >> 16) & 1u)) >> 16;
    return (unsigned short)r;
}
__device__ inline float b2f(unsigned u16) {
    union { unsigned u; float f; } v; v.u = u16 << 16;
    return v.f;
}

__device__ inline void async_load16(const void* g, void* l) {
    __builtin_amdgcn_global_load_lds(
        (const __attribute__((address_space(1))) void*)g,
        (__attribute__((address_space(3))) void*)l, 16, 0, 0);
}

// ---------------------------------------------------------------------------
// W prep: [Wx1 | Wn1] fp32 [256][128]x2 -> bf16, MFMA B-fragment order:
//   frag = kc*16 + nt  (kc<8, nt<16; nt<8 -> Wx cols, nt>=8 -> Wn cols)
//   Wsw[(frag*64 + lane)*8 + j] = Wcat[kc*32 + (lane>>4)*8 + j][nt*16 + (lane&15)]
// ---------------------------------------------------------------------------
__global__ __launch_bounds__(256)
void prep_w(const float* __restrict__ Wx, const float* __restrict__ Wn,
            unsigned short* __restrict__ Wsw) {
    const int t    = blockIdx.x * 256 + threadIdx.x;   // 0..8191
    const int lane = t & 63;
    const int frag = t >> 6;                           // kc*16 + nt
    const int kc = frag >> 4, nt = frag & 15;
    const int quad = lane >> 4, lr = lane & 15;
    unsigned short v[8];
#pragma unroll
    for (int j = 0; j < 8; ++j) {
        int k = kc * 32 + quad * 8 + j;
        int n = nt * 16 + lr;                          // 0..255
        float w = (n < HH) ? Wx[k * HH + n] : Wn[k * HH + (n - HH)];
        v[j] = f2b(w);
    }
    ((uint4*)Wsw)[t] = *(uint4*)v;
}

// ---------------------------------------------------------------------------
// PQ = feat @ [Wx1 | Wn1] -> bf16 [NN][256]
// BM=32, 256 thr (4 waves). Phases:
//  1) async DMA: 32 fp32 rows -> LDS (global_load_lds x16B, 8 rows/wave)
//  2) reg-staged convert fp32 -> bf16 (RNE) into A2 (over dead af region)
//  3) MFMA: wave w owns col-tiles w*4..w*4+3; 8 kc x 4 ntl x 2 rowgroups
//  4) epilogue: acc -> bf16 into disjoint LDS region O, then FULLY
//     COALESCED stores (lanes 0..31 cover one 512B row consecutively).
//     NOTE: no address stagger on anything that reaches global memory —
//     round-4's staggered stores caused 4x HBM write amplification.
// LDS 33.8 KB -> 4 blocks/CU.
// ---------------------------------------------------------------------------
__global__ __launch_bounds__(256, 4)
void pq_gemm(const float* __restrict__ feat,
             const unsigned short* __restrict__ Wsw,
             unsigned short* __restrict__ PQb) {
    constexpr int RSF = 260;   // fp32 row stride
    constexpr int RSB = 264;   // bf16 row stride (528B, 16B aligned)
    __shared__ union {
        float af[32 * RSF];               // 33280 B
        unsigned short ab[2 * 32 * RSB];  // 33792 B  [0..]: A2, [32*RSB..]: O
    } sm;
    unsigned short* const A2 = sm.ab;
    unsigned short* const O  = sm.ab + 32 * RSB;

    const int r0 = blockIdx.x * 32;
    const int t  = threadIdx.x;
    const int wv = t >> 6, lane = t & 63;

    // ---- 1) async stage: rows wv*8..wv*8+7, 1 KB each
#pragma unroll
    for (int i = 0; i < 8; ++i) {
        int row = wv * 8 + i;
        const float* g = feat + (long)(r0 + row) * DD + lane * 4;
        async_load16(g, &sm.af[row * RSF]);
    }
    __syncthreads();

    // ---- 2) convert: thread owns (row = t>>3, seg = t&7) -> 32 floats
    const int crow = t >> 3, cseg = t & 7;
    float4 v[8];
#pragma unroll
    for (int i = 0; i < 8; ++i) {
        int ii = (i + cseg) & 7;                    // LDS-read bank stagger only
        v[ii] = *(float4*)&sm.af[crow * RSF + cseg * 32 + ii * 4];
    }
    __syncthreads();
    unsigned dw[16];
#pragma unroll
    for (int i = 0; i < 8; ++i) {
        dw[2 * i]     = (unsigned)f2b(v[i].x) | ((unsigned)f2b(v[i].y) << 16);
        dw[2 * i + 1] = (unsigned)f2b(v[i].z) | ((unsigned)f2b(v[i].w) << 16);
    }
#pragma unroll
    for (int q = 0; q < 4; ++q)
        *(uint4*)&A2[crow * RSB + cseg * 32 + q * 8] = *(uint4*)&dw[q * 4];
    __syncthreads();

    // ---- 3) MFMA: wave wv -> col tiles wv*4..wv*4+3 (64 cols), 32 rows
    const int quad = lane >> 4, lr = lane & 15;
    f32x4 acc[2][4] = {};
#pragma unroll
    for (int kc = 0; kc < 8; ++kc) {
        bf16x8 a0 = *(const bf16x8*)&A2[(lr)      * RSB + kc * 32 + quad * 8];
        bf16x8 a1 = *(const bf16x8*)&A2[(16 + lr) * RSB + kc * 32 + quad * 8];
#pragma unroll
        for (int ntl = 0; ntl < 4; ++ntl) {
            bf16x8 b = *(const bf16x8*)&Wsw[((kc * 16 + wv * 4 + ntl) * 64 + lane) * 8];
            acc[0][ntl] = __builtin_amdgcn_mfma_f32_16x16x32_bf16(a0, b, acc[0][ntl], 0, 0, 0);
            acc[1][ntl] = __builtin_amdgcn_mfma_f32_16x16x32_bf16(a1, b, acc[1][ntl], 0, 0, 0);
        }
    }

    // ---- 4) epilogue: C/D row=quad*4+r, col=lr; bf16 into O (disjoint)
#pragma unroll
    for (int rg = 0; rg < 2; ++rg)
#pragma unroll
        for (int ntl = 0; ntl < 4; ++ntl) {
            int col = (wv * 4 + ntl) * 16 + lr;
#pragma unroll
            for (int r = 0; r < 4; ++r)
                O[(rg * 16 + quad * 4 + r) * RSB + col] = f2b(acc[rg][ntl][r]);
        }
    __syncthreads();

    // readback + fully coalesced stores: 32 rows x 32 chunks of 16 B
#pragma unroll
    for (int i = 0; i < 4; ++i) {
        int id = i * 256 + t;
        int row = id >> 5, c = id & 31;
        uint4 d = *(uint4*)&O[row * RSB + c * 8];
        *(uint4*)&PQb[(long)(r0 + row) * DD + c * 8] = d;
    }
}

// ---------------------------------------------------------------------------
// build_g1: g1b[row] = bf16(relu([PQ[ids1[row]].X + bx1 | mean_j PQ[ids2].N + bn1]))
// 2 rows per wave (half-wave each, 8 B/lane); 10 neighbor ids via shfl.
// ---------------------------------------------------------------------------
__global__ __launch_bounds__(256)
void build_g1(const unsigned short* __restrict__ PQb,
              const int* __restrict__ ids1, const int* __restrict__ ids2,
              const float* __restrict__ bx1, const float* __restrict__ bn1,
              unsigned short* __restrict__ g1b) {
    const int wv   = threadIdx.x >> 6;
    const int lane = threadIdx.x & 63;
    const int sub  = lane >> 5, lr = lane & 31;
    const int row  = blockIdx.x * 8 + wv * 2 + sub;

    long xr = (long)ids1[row];
    uint2 xv = *(const uint2*)&PQb[xr * DD + lr * 4];

    int myid = ids2[row * SS2 + (lr % SS2)];
    float4 acc = {0.f, 0.f, 0.f, 0.f};
#pragma unroll
    for (int j = 0; j < SS2; ++j) {
        long nr = (long)__shfl(myid, (lane & 32) + j);
        uint2 nv = *(const uint2*)&PQb[nr * DD + HH + lr * 4];
        acc.x += b2f(nv.x & 0xffff); acc.y += b2f(nv.x >> 16);
        acc.z += b2f(nv.y & 0xffff); acc.w += b2f(nv.y >> 16);
    }
    float4 bx = *(const float4*)&bx1[lr * 4];
    float4 bn = *(const float4*)&bn1[lr * 4];
    float x0 = fmaxf(b2f(xv.x & 0xffff) + bx.x, 0.f);
    float x1 = fmaxf(b2f(xv.x >> 16)    + bx.y, 0.f);
    float x2 = fmaxf(b2f(xv.y & 0xffff) + bx.z, 0.f);
    float x3 = fmaxf(b2f(xv.y >> 16)    + bx.w, 0.f);
    constexpr float inv = 1.f / SS2;
    float n0 = fmaxf(acc.x * inv + bn.x, 0.f);
    float n1 = fmaxf(acc.y * inv + bn.y, 0.f);
    float n2 = fmaxf(acc.z * inv + bn.z, 0.f);
    float n3 = fmaxf(acc.w * inv + bn.w, 0.f);

    uint2 ox = { (unsigned)f2b(x0) | ((unsigned)f2b(x1) << 16),
                 (unsigned)f2b(x2) | ((unsigned)f2b(x3) << 16) };
    uint2 on = { (unsigned)f2b(n0) | ((unsigned)f2b(n1) << 16),
                 (unsigned)f2b(n2) | ((unsigned)f2b(n3) << 16) };
    *(uint2*)&g1b[(long)row * DD + lr * 4]      = ox;
    *(uint2*)&g1b[(long)row * DD + HH + lr * 4] = on;
}

// ---------------------------------------------------------------------------
// build_g0: g0[row] = relu([PQ[ids0[row]].X + bx1 | mean_{j<25} PQ[ids1].N + bn1])
// fp32 output; 2 rows per wave.
// ---------------------------------------------------------------------------
__global__ __launch_bounds__(256)
void build_g0(const unsigned short* __restrict__ PQb,
              const int* __restrict__ ids0, const int* __restrict__ ids1,
              const float* __restrict__ bx1, const float* __restrict__ bn1,
              float* __restrict__ g0) {
    const int wv   = threadIdx.x >> 6;
    const int lane = threadIdx.x & 63;
    const int sub  = lane >> 5, lr = lane & 31;
    const int row  = blockIdx.x * 8 + wv * 2 + sub;

    long xr = (long)ids0[row];
    uint2 xv = *(const uint2*)&PQb[xr * DD + lr * 4];

    int myid = ids1[row * SS1 + (lr % SS1)];
    float4 acc = {0.f, 0.f, 0.f, 0.f};
#pragma unroll 5
    for (int j = 0; j < SS1; ++j) {
        long nr = (long)__shfl(myid, (lane & 32) + j);
        uint2 nv = *(const uint2*)&PQb[nr * DD + HH + lr * 4];
        acc.x += b2f(nv.x & 0xffff); acc.y += b2f(nv.x >> 16);
        acc.z += b2f(nv.y & 0xffff); acc.w += b2f(nv.y >> 16);
    }
    float4 bx = *(const float4*)&bx1[lr * 4];
    float4 bn = *(const float4*)&bn1[lr * 4];
    constexpr float inv = 1.f / SS1;
    float4 xo = { fmaxf(b2f(xv.x & 0xffff) + bx.x, 0.f),
                  fmaxf(b2f(xv.x >> 16)    + bx.y, 0.f),
                  fmaxf(b2f(xv.y & 0xffff) + bx.z, 0.f),
                  fmaxf(b2f(xv.y >> 16)    + bx.w, 0.f) };
    float4 no = { fmaxf(acc.x * inv + bn.x, 0.f),
                  fmaxf(acc.y * inv + bn.y, 0.f),
                  fmaxf(acc.z * inv + bn.z, 0.f),
                  fmaxf(acc.w * inv + bn.w, 0.f) };
    *(float4*)&g0[(long)row * DD + lr * 4]      = xo;
    *(float4*)&g0[(long)row * DD + HH + lr * 4] = no;
}

// ---------------------------------------------------------------------------
// agg2 (layer 2, identity act, gm-mean fused):
//   f0[i] = [ g0[i].Wx2 + bx2 | (mean_{j<25} g1b[i*25+j]) . Wn2 + bn2 ]
// ---------------------------------------------------------------------------
__global__ __launch_bounds__(256)
void agg2(const float* __restrict__ g0, const unsigned short* __restrict__ g1b,
          const float* __restrict__ Wx, const float* __restrict__ bx,
          const float* __restrict__ Wn, const float* __restrict__ bn,
          float* __restrict__ f0) {
    constexpr int RT = 16;
    __shared__ float aX[RT][DD];
    __shared__ float aN[RT][DD];
    const int r0 = blockIdx.x * RT;
    const int t  = threadIdx.x;

#pragma unroll
    for (int i = 0; i < 4; ++i) {
        int id = i * 256 + t;
        int r = id >> 6, c4 = (id & 63) * 4;
        *(float4*)&aX[r][c4] = *(const float4*)(g0 + (long)(r0 + r) * DD + c4);
        float4 acc = {0.f, 0.f, 0.f, 0.f};
        const unsigned short* base = g1b + ((long)(r0 + r) * SS1) * DD + c4;
        for (int j = 0; j < SS1; ++j) {
            ushort4 u = *(const ushort4*)(base + (long)j * DD);
            acc.x += b2f(u.x); acc.y += b2f(u.y);
            acc.z += b2f(u.z); acc.w += b2f(u.w);
        }
        acc.x *= (1.f / SS1); acc.y *= (1.f / SS1);
        acc.z *= (1.f / SS1); acc.w *= (1.f / SS1);
        *(float4*)&aN[r][c4] = acc;
    }
    __syncthreads();

    const bool xhalf = (t < HH);
    const float* __restrict__ W = xhalf ? Wx : Wn;
    const float (* __restrict__ A)[DD] = xhalf ? aX : aN;
    const int c = t & (HH - 1);

    float acc[RT];
#pragma unroll
    for (int r = 0; r < RT; ++r) acc[r] = 0.f;
#pragma unroll 4
    for (int k = 0; k < DD; ++k) {
        float wv = W[k * HH + c];
#pragma unroll
        for (int r = 0; r < RT; ++r) acc[r] += A[r][k] * wv;
    }
    const float bias = xhalf ? bx[c] : bn[c];
#pragma unroll
    for (int r = 0; r < RT; ++r)
        f0[(long)(r0 + r) * DD + t] = acc[r] + bias;
}

// ---------------------------------------------------------------------------
// head: out[1024][64] = f0 @ Wfc + bfc
// ---------------------------------------------------------------------------
__global__ __launch_bounds__(256)
void head_kernel(const float* __restrict__ f0, const float* __restrict__ Wfc,
                 const float* __restrict__ bfc, float* __restrict__ out) {
    constexpr int RT = 16;
    __shared__ float aX[64][DD];
    const int r0 = blockIdx.x * 64;
    const int t  = threadIdx.x;

    for (int basei = 0; basei < 64 * DD; basei += 1024) {
        int idx = basei + t * 4;
        int r = idx >> 8, k = idx & 255;
        *(float4*)&aX[r][k] = *(const float4*)(f0 + (long)(r0 + r) * DD + k);
    }
    __syncthreads();

    const int c  = t & (CC - 1);
    const int rg = t >> 6;
    float acc[RT];
#pragma unroll
    for (int r = 0; r < RT; ++r) acc[r] = 0.f;
#pragma unroll 4
    for (int k = 0; k < DD; ++k) {
        float wv = Wfc[k * CC + c];
#pragma unroll
        for (int r = 0; r < RT; ++r) acc[r] += aX[rg * RT + r][k] * wv;
    }
    const float bias = bfc[c];
#pragma unroll
    for (int r = 0; r < RT; ++r)
        out[(long)(r0 + rg * RT + r) * CC + c] = acc[r] + bias;
}

// ---------------------------------------------------------------------------
extern "C" void kernel_launch(void* const* d_in, const int* in_sizes, int n_in,
                              void* d_out, int out_size, void* d_ws, size_t ws_size,
                              hipStream_t stream) {
    const int*   ids0 = (const int*)d_in[0];
    const int*   ids1 = (const int*)d_in[1];
    const int*   ids2 = (const int*)d_in[2];
    const float* feat = (const float*)d_in[3];
    const float* Wx1  = (const float*)d_in[4];
    const float* bx1  = (const float*)d_in[5];
    const float* Wn1  = (const float*)d_in[6];
    const float* bn1  = (const float*)d_in[7];
    const float* Wx2  = (const float*)d_in[8];
    const float* bx2  = (const float*)d_in[9];
    const float* Wn2  = (const float*)d_in[10];
    const float* bn2  = (const float*)d_in[11];
    const float* Wfc  = (const float*)d_in[12];
    const float* bfc  = (const float*)d_in[13];
    float* out = (float*)d_out;

    const long M1 = (long)BB * SS1;                      // 25600
    float* wsf = (float*)d_ws;
    float* g0 = wsf;  wsf += (long)BB * DD;              // 1 MB
    float* f0 = wsf;  wsf += (long)BB * DD;              // 1 MB
    unsigned short* PQb = (unsigned short*)wsf;          // 51.2 MB
    unsigned short* g1b = PQb + (long)NN * DD;           // 13.1 MB
    unsigned short* Wsw = g1b + M1 * DD;                 // 128 KB

    // 1) W prep (bf16 + B-fragment swizzle of [Wx1|Wn1])
    prep_w<<<32, 256, 0, stream>>>(Wx1, Wn1, Wsw);
    // 2) PQ = feat @ [Wx1|Wn1]  (bf16)                  [100000,256]
    pq_gemm<<<NN / 32, 256, 0, stream>>>(feat, Wsw, PQb);
    // 3) g1 (bf16)                                      [25600,256]
    build_g1<<<M1 / 8, 256, 0, stream>>>(PQb, ids1, ids2, bx1, bn1, g1b);
    // 4) g0 (fp32)                                      [1024,256]
    build_g0<<<BB / 8, 256, 0, stream>>>(PQb, ids0, ids1, bx1, bn1, g0);
    // 5) f0 = [g0.Wx2 | mean(g1).Wn2] (gm fused)        [1024,256]
    agg2<<<BB / 16, 256, 0, stream>>>(g0, g1b, Wx2, bx2, Wn2, bn2, f0);
    // 6) out = f0 @ Wfc + bfc                           [1024,64]
    head_kernel<<<BB / 64, 256, 0, stream>>>(f0, Wfc, bfc, out);
}

// Round 6
// 280.673 us; speedup vs baseline: 1.4445x; 1.3738x over previous
//
#include <hip/hip_runtime.h>

#define DD 256   // in_dim (= 2H)
#define HH 128   // per-branch out dim
#define CC 64    // n_class
#define BB 1024
#define SS1 25
#define SS2 10
#define NN 100000

typedef __attribute__((ext_vector_type(8))) short bf16x8;
typedef __attribute__((ext_vector_type(4))) float f32x4;

__device__ inline unsigned short f2b(float x) {
    union { float f; unsigned u; } v; v.f = x;
    unsigned r = (v.u + 0x7fffu + ((v.u >> 16) & 1u)) >> 16;
    return (unsigned short)r;
}
__device__ inline float b2f(unsigned u16) {
    union { unsigned u; float f; } v; v.u = u16 << 16;
    return v.f;
}

// ---------------------------------------------------------------------------
// W prep: [Wx1 | Wn1] fp32 [256][128]x2 -> bf16, MFMA B-fragment order:
//   frag = kc*16 + nt  (kc<8, nt<16; nt<8 -> Wx cols, nt>=8 -> Wn cols)
//   Wsw[(frag*64 + lane)*8 + j] = Wcat[kc*32 + (lane>>4)*8 + j][nt*16 + (lane&15)]
// ---------------------------------------------------------------------------
__global__ __launch_bounds__(256)
void prep_w(const float* __restrict__ Wx, const float* __restrict__ Wn,
            unsigned short* __restrict__ Wsw) {
    const int t    = blockIdx.x * 256 + threadIdx.x;   // 0..8191
    const int lane = t & 63;
    const int frag = t >> 6;                           // kc*16 + nt
    const int kc = frag >> 4, nt = frag & 15;
    const int quad = lane >> 4, lr = lane & 15;
    unsigned short v[8];
#pragma unroll
    for (int j = 0; j < 8; ++j) {
        int k = kc * 32 + quad * 8 + j;
        int n = nt * 16 + lr;                          // 0..255
        float w = (n < HH) ? Wx[k * HH + n] : Wn[k * HH + (n - HH)];
        v[j] = f2b(w);
    }
    ((uint4*)Wsw)[t] = *(uint4*)v;
}

// ---------------------------------------------------------------------------
// PQ = feat @ [Wx1 | Wn1] -> bf16 [NN][256]
// Round-3 structure (proven 84 us, clean HBM traffic) + LDS fix:
//  - BM=64, 256 thr (4 waves). Staging via REGULAR float4 loads (these
//    allocate in L2/L3 -> feat stays partially L3-resident across launches;
//    the global_load_lds DMA path of rounds 4/5 bypassed L3 and doubled
//    FETCH + caused dirty-eviction write traffic).
//  - Epilogue: acc -> bf16 in registers, REUSES the 33.8 KB A-region as the
//    output staging buffer (round 3 used a 65 KB fp32 union -> 2 blocks/CU;
//    now 33.8 KB total -> 4 blocks/CU).
// Wave w: row-pair rp=w&1 (32 rows), col-half ch=w>>1 (8 col-tiles).
// ---------------------------------------------------------------------------
__global__ __launch_bounds__(256, 4)
void pq_gemm(const float* __restrict__ feat,
             const unsigned short* __restrict__ Wsw,
             unsigned short* __restrict__ PQb) {
    constexpr int AS = 264;                 // bf16 row stride (528 B)
    __shared__ unsigned short sA[64 * AS];  // 33792 B; A-tile, then O-tile
    const int r0 = blockIdx.x * 64;
    const int t  = threadIdx.x;

    // ---- 1) stage A: 64 rows x 32 chunks of 8 floats -> bf16 (coalesced)
#pragma unroll
    for (int i = 0; i < 8; ++i) {
        int id = i * 256 + t;
        int row = id >> 5, c = id & 31;
        long gr = r0 + row; if (gr > NN - 1) gr = NN - 1;
        const float* src = feat + gr * DD + c * 8;
        float4 v0 = ((const float4*)src)[0];
        float4 v1 = ((const float4*)src)[1];
        unsigned short w8[8] = { f2b(v0.x), f2b(v0.y), f2b(v0.z), f2b(v0.w),
                                 f2b(v1.x), f2b(v1.y), f2b(v1.z), f2b(v1.w) };
        *(uint4*)&sA[row * AS + c * 8] = *(uint4*)w8;
    }
    __syncthreads();

    // ---- 2) MFMA: wave w -> rows rp*32..+32, col tiles ch*8..+8
    const int w = t >> 6, lane = t & 63;
    const int quad = lane >> 4, lr = lane & 15;
    const int rp = w & 1, ch = w >> 1;

    f32x4 acc[2][8] = {};
#pragma unroll
    for (int kc = 0; kc < 8; ++kc) {
        bf16x8 a0 = *(const bf16x8*)&sA[(rp * 32 + lr) * AS + kc * 32 + quad * 8];
        bf16x8 a1 = *(const bf16x8*)&sA[(rp * 32 + 16 + lr) * AS + kc * 32 + quad * 8];
#pragma unroll
        for (int ntl = 0; ntl < 8; ++ntl) {
            bf16x8 b = *(const bf16x8*)&Wsw[((kc * 16 + ch * 8 + ntl) * 64 + lane) * 8];
            acc[0][ntl] = __builtin_amdgcn_mfma_f32_16x16x32_bf16(a0, b, acc[0][ntl], 0, 0, 0);
            acc[1][ntl] = __builtin_amdgcn_mfma_f32_16x16x32_bf16(a1, b, acc[1][ntl], 0, 0, 0);
        }
    }
    __syncthreads();   // all waves done reading sA -> safe to overwrite as O

    // ---- 3) epilogue: acc -> bf16 into sA (C layout: row=quad*4+r, col=lr)
#pragma unroll
    for (int rg = 0; rg < 2; ++rg)
#pragma unroll
        for (int ntl = 0; ntl < 8; ++ntl) {
            int col = (ch * 8 + ntl) * 16 + lr;
#pragma unroll
            for (int r = 0; r < 4; ++r)
                sA[(rp * 32 + rg * 16 + quad * 4 + r) * AS + col]
                    = f2b(acc[rg][ntl][r]);
        }
    __syncthreads();

    // ---- 4) readback + fully coalesced stores: 64 rows x 32 chunks of 16 B
#pragma unroll
    for (int i = 0; i < 8; ++i) {
        int id = i * 256 + t;
        int row = id >> 5, c = id & 31;
        long gr = r0 + row;
        if (gr < NN) {
            uint4 d = *(uint4*)&sA[row * AS + c * 8];
            *(uint4*)&PQb[gr * DD + c * 8] = d;
        }
    }
}

// ---------------------------------------------------------------------------
// build_g1: g1b[row] = bf16(relu([PQ[ids1[row]].X + bx1 | mean_j PQ[ids2].N + bn1]))
// 2 rows per wave (half-wave each, 8 B/lane); 10 neighbor ids via shfl.
// ---------------------------------------------------------------------------
__global__ __launch_bounds__(256)
void build_g1(const unsigned short* __restrict__ PQb,
              const int* __restrict__ ids1, const int* __restrict__ ids2,
              const float* __restrict__ bx1, const float* __restrict__ bn1,
              unsigned short* __restrict__ g1b) {
    const int wv   = threadIdx.x >> 6;
    const int lane = threadIdx.x & 63;
    const int sub  = lane >> 5, lr = lane & 31;
    const int row  = blockIdx.x * 8 + wv * 2 + sub;

    long xr = (long)ids1[row];
    uint2 xv = *(const uint2*)&PQb[xr * DD + lr * 4];

    int myid = ids2[row * SS2 + (lr % SS2)];
    float4 acc = {0.f, 0.f, 0.f, 0.f};
#pragma unroll
    for (int j = 0; j < SS2; ++j) {
        long nr = (long)__shfl(myid, (lane & 32) + j);
        uint2 nv = *(const uint2*)&PQb[nr * DD + HH + lr * 4];
        acc.x += b2f(nv.x & 0xffff); acc.y += b2f(nv.x >> 16);
        acc.z += b2f(nv.y & 0xffff); acc.w += b2f(nv.y >> 16);
    }
    float4 bx = *(const float4*)&bx1[lr * 4];
    float4 bn = *(const float4*)&bn1[lr * 4];
    float x0 = fmaxf(b2f(xv.x & 0xffff) + bx.x, 0.f);
    float x1 = fmaxf(b2f(xv.x >> 16)    + bx.y, 0.f);
    float x2 = fmaxf(b2f(xv.y & 0xffff) + bx.z, 0.f);
    float x3 = fmaxf(b2f(xv.y >> 16)    + bx.w, 0.f);
    constexpr float inv = 1.f / SS2;
    float n0 = fmaxf(acc.x * inv + bn.x, 0.f);
    float n1 = fmaxf(acc.y * inv + bn.y, 0.f);
    float n2 = fmaxf(acc.z * inv + bn.z, 0.f);
    float n3 = fmaxf(acc.w * inv + bn.w, 0.f);

    uint2 ox = { (unsigned)f2b(x0) | ((unsigned)f2b(x1) << 16),
                 (unsigned)f2b(x2) | ((unsigned)f2b(x3) << 16) };
    uint2 on = { (unsigned)f2b(n0) | ((unsigned)f2b(n1) << 16),
                 (unsigned)f2b(n2) | ((unsigned)f2b(n3) << 16) };
    *(uint2*)&g1b[(long)row * DD + lr * 4]      = ox;
    *(uint2*)&g1b[(long)row * DD + HH + lr * 4] = on;
}

// ---------------------------------------------------------------------------
// build_g0: g0[row] = relu([PQ[ids0[row]].X + bx1 | mean_{j<25} PQ[ids1].N + bn1])
// fp32 output; 2 rows per wave.
// ---------------------------------------------------------------------------
__global__ __launch_bounds__(256)
void build_g0(const unsigned short* __restrict__ PQb,
              const int* __restrict__ ids0, const int* __restrict__ ids1,
              const float* __restrict__ bx1, const float* __restrict__ bn1,
              float* __restrict__ g0) {
    const int wv   = threadIdx.x >> 6;
    const int lane = threadIdx.x & 63;
    const int sub  = lane >> 5, lr = lane & 31;
    const int row  = blockIdx.x * 8 + wv * 2 + sub;

    long xr = (long)ids0[row];
    uint2 xv = *(const uint2*)&PQb[xr * DD + lr * 4];

    int myid = ids1[row * SS1 + (lr % SS1)];
    float4 acc = {0.f, 0.f, 0.f, 0.f};
#pragma unroll 5
    for (int j = 0; j < SS1; ++j) {
        long nr = (long)__shfl(myid, (lane & 32) + j);
        uint2 nv = *(const uint2*)&PQb[nr * DD + HH + lr * 4];
        acc.x += b2f(nv.x & 0xffff); acc.y += b2f(nv.x >> 16);
        acc.z += b2f(nv.y & 0xffff); acc.w += b2f(nv.y >> 16);
    }
    float4 bx = *(const float4*)&bx1[lr * 4];
    float4 bn = *(const float4*)&bn1[lr * 4];
    constexpr float inv = 1.f / SS1;
    float4 xo = { fmaxf(b2f(xv.x & 0xffff) + bx.x, 0.f),
                  fmaxf(b2f(xv.x >> 16)    + bx.y, 0.f),
                  fmaxf(b2f(xv.y & 0xffff) + bx.z, 0.f),
                  fmaxf(b2f(xv.y >> 16)    + bx.w, 0.f) };
    float4 no = { fmaxf(acc.x * inv + bn.x, 0.f),
                  fmaxf(acc.y * inv + bn.y, 0.f),
                  fmaxf(acc.z * inv + bn.z, 0.f),
                  fmaxf(acc.w * inv + bn.w, 0.f) };
    *(float4*)&g0[(long)row * DD + lr * 4]      = xo;
    *(float4*)&g0[(long)row * DD + HH + lr * 4] = no;
}

// ---------------------------------------------------------------------------
// agg2 (layer 2, identity act, gm-mean fused):
//   f0[i] = [ g0[i].Wx2 + bx2 | (mean_{j<25} g1b[i*25+j]) . Wn2 + bn2 ]
// ---------------------------------------------------------------------------
__global__ __launch_bounds__(256)
void agg2(const float* __restrict__ g0, const unsigned short* __restrict__ g1b,
          const float* __restrict__ Wx, const float* __restrict__ bx,
          const float* __restrict__ Wn, const float* __restrict__ bn,
          float* __restrict__ f0) {
    constexpr int RT = 16;
    __shared__ float aX[RT][DD];
    __shared__ float aN[RT][DD];
    const int r0 = blockIdx.x * RT;
    const int t  = threadIdx.x;

#pragma unroll
    for (int i = 0; i < 4; ++i) {
        int id = i * 256 + t;
        int r = id >> 6, c4 = (id & 63) * 4;
        *(float4*)&aX[r][c4] = *(const float4*)(g0 + (long)(r0 + r) * DD + c4);
        float4 acc = {0.f, 0.f, 0.f, 0.f};
        const unsigned short* base = g1b + ((long)(r0 + r) * SS1) * DD + c4;
        for (int j = 0; j < SS1; ++j) {
            ushort4 u = *(const ushort4*)(base + (long)j * DD);
            acc.x += b2f(u.x); acc.y += b2f(u.y);
            acc.z += b2f(u.z); acc.w += b2f(u.w);
        }
        acc.x *= (1.f / SS1); acc.y *= (1.f / SS1);
        acc.z *= (1.f / SS1); acc.w *= (1.f / SS1);
        *(float4*)&aN[r][c4] = acc;
    }
    __syncthreads();

    const bool xhalf = (t < HH);
    const float* __restrict__ W = xhalf ? Wx : Wn;
    const float (* __restrict__ A)[DD] = xhalf ? aX : aN;
    const int c = t & (HH - 1);

    float acc[RT];
#pragma unroll
    for (int r = 0; r < RT; ++r) acc[r] = 0.f;
#pragma unroll 4
    for (int k = 0; k < DD; ++k) {
        float wv = W[k * HH + c];
#pragma unroll
        for (int r = 0; r < RT; ++r) acc[r] += A[r][k] * wv;
    }
    const float bias = xhalf ? bx[c] : bn[c];
#pragma unroll
    for (int r = 0; r < RT; ++r)
        f0[(long)(r0 + r) * DD + t] = acc[r] + bias;
}

// ---------------------------------------------------------------------------
// head: out[1024][64] = f0 @ Wfc + bfc
// ---------------------------------------------------------------------------
__global__ __launch_bounds__(256)
void head_kernel(const float* __restrict__ f0, const float* __restrict__ Wfc,
                 const float* __restrict__ bfc, float* __restrict__ out) {
    constexpr int RT = 16;
    __shared__ float aX[64][DD];
    const int r0 = blockIdx.x * 64;
    const int t  = threadIdx.x;

    for (int basei = 0; basei < 64 * DD; basei += 1024) {
        int idx = basei + t * 4;
        int r = idx >> 8, k = idx & 255;
        *(float4*)&aX[r][k] = *(const float4*)(f0 + (long)(r0 + r) * DD + k);
    }
    __syncthreads();

    const int c  = t & (CC - 1);
    const int rg = t >> 6;
    float acc[RT];
#pragma unroll
    for (int r = 0; r < RT; ++r) acc[r] = 0.f;
#pragma unroll 4
    for (int k = 0; k < DD; ++k) {
        float wv = Wfc[k * CC + c];
#pragma unroll
        for (int r = 0; r < RT; ++r) acc[r] += aX[rg * RT + r][k] * wv;
    }
    const float bias = bfc[c];
#pragma unroll
    for (int r = 0; r < RT; ++r)
        out[(long)(r0 + rg * RT + r) * CC + c] = acc[r] + bias;
}

// ---------------------------------------------------------------------------
extern "C" void kernel_launch(void* const* d_in, const int* in_sizes, int n_in,
                              void* d_out, int out_size, void* d_ws, size_t ws_size,
                              hipStream_t stream) {
    const int*   ids0 = (const int*)d_in[0];
    const int*   ids1 = (const int*)d_in[1];
    const int*   ids2 = (const int*)d_in[2];
    const float* feat = (const float*)d_in[3];
    const float* Wx1  = (const float*)d_in[4];
    const float* bx1  = (const float*)d_in[5];
    const float* Wn1  = (const float*)d_in[6];
    const float* bn1  = (const float*)d_in[7];
    const float* Wx2  = (const float*)d_in[8];
    const float* bx2  = (const float*)d_in[9];
    const float* Wn2  = (const float*)d_in[10];
    const float* bn2  = (const float*)d_in[11];
    const float* Wfc  = (const float*)d_in[12];
    const float* bfc  = (const float*)d_in[13];
    float* out = (float*)d_out;

    const long M1 = (long)BB * SS1;                      // 25600
    float* wsf = (float*)d_ws;
    float* g0 = wsf;  wsf += (long)BB * DD;              // 1 MB
    float* f0 = wsf;  wsf += (long)BB * DD;              // 1 MB
    unsigned short* PQb = (unsigned short*)wsf;          // 51.2 MB
    unsigned short* g1b = PQb + (long)NN * DD;           // 13.1 MB
    unsigned short* Wsw = g1b + M1 * DD;                 // 128 KB

    // 1) W prep (bf16 + B-fragment swizzle of [Wx1|Wn1])
    prep_w<<<32, 256, 0, stream>>>(Wx1, Wn1, Wsw);
    // 2) PQ = feat @ [Wx1|Wn1]  (bf16)                  [100000,256]
    pq_gemm<<<(NN + 63) / 64, 256, 0, stream>>>(feat, Wsw, PQb);
    // 3) g1 (bf16)                                      [25600,256]
    build_g1<<<M1 / 8, 256, 0, stream>>>(PQb, ids1, ids2, bx1, bn1, g1b);
    // 4) g0 (fp32)                                      [1024,256]
    build_g0<<<BB / 8, 256, 0, stream>>>(PQb, ids0, ids1, bx1, bn1, g0);
    // 5) f0 = [g0.Wx2 | mean(g1).Wn2] (gm fused)        [1024,256]
    agg2<<<BB / 16, 256, 0, stream>>>(g0, g1b, Wx2, bx2, Wn2, bn2, f0);
    // 6) out = f0 @ Wfc + bfc                           [1024,64]
    head_kernel<<<BB / 64, 256, 0, stream>>>(f0, Wfc, bfc, out);
}

// Round 7
// 276.989 us; speedup vs baseline: 1.4637x; 1.0133x over previous
//
#include <hip/hip_runtime.h>

#define DD 256   // in_dim (= 2H)
#define HH 128   // per-branch out dim
#define CC 64    // n_class
#define BB 1024
#define SS1 25
#define SS2 10
#define NN 100000

typedef __attribute__((ext_vector_type(8))) short bf16x8;
typedef __attribute__((ext_vector_type(4))) float f32x4;

__device__ inline unsigned short f2b(float x) {
    union { float f; unsigned u; } v; v.f = x;
    unsigned r = (v.u + 0x7fffu + ((v.u >> 16) & 1u)) >> 16;
    return (unsigned short)r;
}
__device__ inline float b2f(unsigned u16) {
    union { unsigned u; float f; } v; v.u = u16 << 16;
    return v.f;
}

// ---------------------------------------------------------------------------
// W prep: [Wx1 | Wn1] fp32 [256][128]x2 -> bf16, MFMA B-fragment order:
//   frag = kc*16 + nt  (kc<8, nt<16; nt<8 -> Wx cols, nt>=8 -> Wn cols)
//   Wsw[(frag*64 + lane)*8 + j] = Wcat[kc*32 + (lane>>4)*8 + j][nt*16 + (lane&15)]
// ---------------------------------------------------------------------------
__global__ __launch_bounds__(256)
void prep_w(const float* __restrict__ Wx, const float* __restrict__ Wn,
            unsigned short* __restrict__ Wsw) {
    const int t    = blockIdx.x * 256 + threadIdx.x;   // 0..8191
    const int lane = t & 63;
    const int frag = t >> 6;                           // kc*16 + nt
    const int kc = frag >> 4, nt = frag & 15;
    const int quad = lane >> 4, lr = lane & 15;
    unsigned short v[8];
#pragma unroll
    for (int j = 0; j < 8; ++j) {
        int k = kc * 32 + quad * 8 + j;
        int n = nt * 16 + lr;                          // 0..255
        float w = (n < HH) ? Wx[k * HH + n] : Wn[k * HH + (n - HH)];
        v[j] = f2b(w);
    }
    ((uint4*)Wsw)[t] = *(uint4*)v;
}

// ---------------------------------------------------------------------------
// PQ = feat @ [Wx1 | Wn1] -> bf16 [NN][256]
// BM=64, 4 waves, regular vector loads (L2/L3-friendly; DMA path regressed).
// v4: staging loads REGISTER-BATCHED — all 16 global_load_dwordx4 issued
// into float4 v[16] before any convert/LDS write, so one vmcnt drain covers
// 16 in-flight loads (round-6 compiled to ~2 in flight -> latency-bound,
// 1.66 TB/s). VGPR ~100 < 128 budget at 4 blocks/CU.
// Epilogue reuses the A-region (33.8 KB total -> 4 blocks/CU).
// ---------------------------------------------------------------------------
__global__ __launch_bounds__(256, 4)
void pq_gemm(const float* __restrict__ feat,
             const unsigned short* __restrict__ Wsw,
             unsigned short* __restrict__ PQb) {
    constexpr int AS = 264;                 // bf16 row stride (528 B)
    __shared__ unsigned short sA[64 * AS];  // 33792 B; A-tile, then O-tile
    const int r0 = blockIdx.x * 64;
    const int t  = threadIdx.x;

    // ---- 1a) issue ALL staging loads (rows i*8 + t>>5, chunk t&31)
    const int srow = t >> 5, sc = t & 31;
    float4 v[16];
#pragma unroll
    for (int i = 0; i < 8; ++i) {
        long gr = r0 + i * 8 + srow; if (gr > NN - 1) gr = NN - 1;
        const float4* src = (const float4*)(feat + gr * DD + sc * 8);
        v[2 * i]     = src[0];
        v[2 * i + 1] = src[1];
    }
    // ---- 1b) convert + LDS write (single drain of the 16 loads)
#pragma unroll
    for (int i = 0; i < 8; ++i) {
        int row = i * 8 + srow;
        float4 a = v[2 * i], b = v[2 * i + 1];
        unsigned short w8[8] = { f2b(a.x), f2b(a.y), f2b(a.z), f2b(a.w),
                                 f2b(b.x), f2b(b.y), f2b(b.z), f2b(b.w) };
        *(uint4*)&sA[row * AS + sc * 8] = *(uint4*)w8;
    }
    __syncthreads();

    // ---- 2) MFMA: wave w -> rows rp*32..+32, col tiles ch*8..+8
    const int w = t >> 6, lane = t & 63;
    const int quad = lane >> 4, lr = lane & 15;
    const int rp = w & 1, ch = w >> 1;

    f32x4 acc[2][8] = {};
#pragma unroll
    for (int kc = 0; kc < 8; ++kc) {
        bf16x8 a0 = *(const bf16x8*)&sA[(rp * 32 + lr) * AS + kc * 32 + quad * 8];
        bf16x8 a1 = *(const bf16x8*)&sA[(rp * 32 + 16 + lr) * AS + kc * 32 + quad * 8];
#pragma unroll
        for (int ntl = 0; ntl < 8; ++ntl) {
            bf16x8 b = *(const bf16x8*)&Wsw[((kc * 16 + ch * 8 + ntl) * 64 + lane) * 8];
            acc[0][ntl] = __builtin_amdgcn_mfma_f32_16x16x32_bf16(a0, b, acc[0][ntl], 0, 0, 0);
            acc[1][ntl] = __builtin_amdgcn_mfma_f32_16x16x32_bf16(a1, b, acc[1][ntl], 0, 0, 0);
        }
    }
    __syncthreads();   // all waves done reading sA -> safe to overwrite as O

    // ---- 3) epilogue: acc -> bf16 into sA (C layout: row=quad*4+r, col=lr)
#pragma unroll
    for (int rg = 0; rg < 2; ++rg)
#pragma unroll
        for (int ntl = 0; ntl < 8; ++ntl) {
            int col = (ch * 8 + ntl) * 16 + lr;
#pragma unroll
            for (int r = 0; r < 4; ++r)
                sA[(rp * 32 + rg * 16 + quad * 4 + r) * AS + col]
                    = f2b(acc[rg][ntl][r]);
        }
    __syncthreads();

    // ---- 4) readback + fully coalesced stores: 64 rows x 32 chunks of 16 B
#pragma unroll
    for (int i = 0; i < 8; ++i) {
        int id = i * 256 + t;
        int row = id >> 5, c = id & 31;
        long gr = r0 + row;
        if (gr < NN) {
            uint4 d = *(uint4*)&sA[row * AS + c * 8];
            *(uint4*)&PQb[gr * DD + c * 8] = d;
        }
    }
}

// ---------------------------------------------------------------------------
// build_g1: g1b[row] = bf16(relu([PQ[ids1[row]].X + bx1 | mean_j PQ[ids2].N + bn1]))
// 2 rows per wave (half-wave each, 8 B/lane); 10 neighbor ids via shfl.
// ---------------------------------------------------------------------------
__global__ __launch_bounds__(256)
void build_g1(const unsigned short* __restrict__ PQb,
              const int* __restrict__ ids1, const int* __restrict__ ids2,
              const float* __restrict__ bx1, const float* __restrict__ bn1,
              unsigned short* __restrict__ g1b) {
    const int wv   = threadIdx.x >> 6;
    const int lane = threadIdx.x & 63;
    const int sub  = lane >> 5, lr = lane & 31;
    const int row  = blockIdx.x * 8 + wv * 2 + sub;

    long xr = (long)ids1[row];
    uint2 xv = *(const uint2*)&PQb[xr * DD + lr * 4];

    int myid = ids2[row * SS2 + (lr % SS2)];
    float4 acc = {0.f, 0.f, 0.f, 0.f};
#pragma unroll
    for (int j = 0; j < SS2; ++j) {
        long nr = (long)__shfl(myid, (lane & 32) + j);
        uint2 nv = *(const uint2*)&PQb[nr * DD + HH + lr * 4];
        acc.x += b2f(nv.x & 0xffff); acc.y += b2f(nv.x >> 16);
        acc.z += b2f(nv.y & 0xffff); acc.w += b2f(nv.y >> 16);
    }
    float4 bx = *(const float4*)&bx1[lr * 4];
    float4 bn = *(const float4*)&bn1[lr * 4];
    float x0 = fmaxf(b2f(xv.x & 0xffff) + bx.x, 0.f);
    float x1 = fmaxf(b2f(xv.x >> 16)    + bx.y, 0.f);
    float x2 = fmaxf(b2f(xv.y & 0xffff) + bx.z, 0.f);
    float x3 = fmaxf(b2f(xv.y >> 16)    + bx.w, 0.f);
    constexpr float inv = 1.f / SS2;
    float n0 = fmaxf(acc.x * inv + bn.x, 0.f);
    float n1 = fmaxf(acc.y * inv + bn.y, 0.f);
    float n2 = fmaxf(acc.z * inv + bn.z, 0.f);
    float n3 = fmaxf(acc.w * inv + bn.w, 0.f);

    uint2 ox = { (unsigned)f2b(x0) | ((unsigned)f2b(x1) << 16),
                 (unsigned)f2b(x2) | ((unsigned)f2b(x3) << 16) };
    uint2 on = { (unsigned)f2b(n0) | ((unsigned)f2b(n1) << 16),
                 (unsigned)f2b(n2) | ((unsigned)f2b(n3) << 16) };
    *(uint2*)&g1b[(long)row * DD + lr * 4]      = ox;
    *(uint2*)&g1b[(long)row * DD + HH + lr * 4] = on;
}

// ---------------------------------------------------------------------------
// build_g0: g0[row] = relu([PQ[ids0[row]].X + bx1 | mean_{j<25} PQ[ids1].N + bn1])
// fp32 output; 2 rows per wave.
// ---------------------------------------------------------------------------
__global__ __launch_bounds__(256)
void build_g0(const unsigned short* __restrict__ PQb,
              const int* __restrict__ ids0, const int* __restrict__ ids1,
              const float* __restrict__ bx1, const float* __restrict__ bn1,
              float* __restrict__ g0) {
    const int wv   = threadIdx.x >> 6;
    const int lane = threadIdx.x & 63;
    const int sub  = lane >> 5, lr = lane & 31;
    const int row  = blockIdx.x * 8 + wv * 2 + sub;

    long xr = (long)ids0[row];
    uint2 xv = *(const uint2*)&PQb[xr * DD + lr * 4];

    int myid = ids1[row * SS1 + (lr % SS1)];
    float4 acc = {0.f, 0.f, 0.f, 0.f};
#pragma unroll 5
    for (int j = 0; j < SS1; ++j) {
        long nr = (long)__shfl(myid, (lane & 32) + j);
        uint2 nv = *(const uint2*)&PQb[nr * DD + HH + lr * 4];
        acc.x += b2f(nv.x & 0xffff); acc.y += b2f(nv.x >> 16);
        acc.z += b2f(nv.y & 0xffff); acc.w += b2f(nv.y >> 16);
    }
    float4 bx = *(const float4*)&bx1[lr * 4];
    float4 bn = *(const float4*)&bn1[lr * 4];
    constexpr float inv = 1.f / SS1;
    float4 xo = { fmaxf(b2f(xv.x & 0xffff) + bx.x, 0.f),
                  fmaxf(b2f(xv.x >> 16)    + bx.y, 0.f),
                  fmaxf(b2f(xv.y & 0xffff) + bx.z, 0.f),
                  fmaxf(b2f(xv.y >> 16)    + bx.w, 0.f) };
    float4 no = { fmaxf(acc.x * inv + bn.x, 0.f),
                  fmaxf(acc.y * inv + bn.y, 0.f),
                  fmaxf(acc.z * inv + bn.z, 0.f),
                  fmaxf(acc.w * inv + bn.w, 0.f) };
    *(float4*)&g0[(long)row * DD + lr * 4]      = xo;
    *(float4*)&g0[(long)row * DD + HH + lr * 4] = no;
}

// ---------------------------------------------------------------------------
// gm_mean: gm[i][:] = mean over SS1 of g1b rows (bf16 -> fp32), 4 rows/block
// 256 blocks -> full-GPU parallel (was fused in 64-block agg2).
// ---------------------------------------------------------------------------
__global__ __launch_bounds__(256)
void gm_mean(const unsigned short* __restrict__ g1b, float* __restrict__ gm) {
    const int row  = blockIdx.x * 4 + (threadIdx.x >> 6);
    const int lane = threadIdx.x & 63;
    const unsigned short* base = g1b + (long)row * SS1 * DD + lane * 4;
    float4 acc = {0.f, 0.f, 0.f, 0.f};
#pragma unroll 5
    for (int j = 0; j < SS1; ++j) {
        uint2 u = *(const uint2*)(base + (long)j * DD);
        acc.x += b2f(u.x & 0xffff); acc.y += b2f(u.x >> 16);
        acc.z += b2f(u.y & 0xffff); acc.w += b2f(u.y >> 16);
    }
    constexpr float inv = 1.f / SS1;
    float4 o = { acc.x * inv, acc.y * inv, acc.z * inv, acc.w * inv };
    *(float4*)&gm[(long)row * DD + lane * 4] = o;
}

// ---------------------------------------------------------------------------
// agg2 v2 (column-split, 64x2 grid = 128 blocks):
//   by=0: f0[i][0:128]   = g0[i] . Wx2 + bx2
//   by=1: f0[i][128:256] = gm[i] . Wn2 + bn2
// Block: 16 rows; 256 thr = 128 cols x 2 row-halves (8 rows each).
// ---------------------------------------------------------------------------
__global__ __launch_bounds__(256)
void agg2(const float* __restrict__ g0, const float* __restrict__ gm,
          const float* __restrict__ Wx, const float* __restrict__ bx,
          const float* __restrict__ Wn, const float* __restrict__ bn,
          float* __restrict__ f0) {
    constexpr int RT = 16;
    __shared__ float A[RT][DD];
    const int r0 = blockIdx.x * RT;
    const int by = blockIdx.y;                 // 0=X half, 1=N half
    const int t  = threadIdx.x;
    const float* __restrict__ src = by ? gm : g0;
    const float* __restrict__ W   = by ? Wn : Wx;
    const float* __restrict__ bb  = by ? bn : bx;

#pragma unroll
    for (int i = 0; i < 4; ++i) {
        int id = i * 256 + t;
        int r = id >> 6, c4 = (id & 63) * 4;
        *(float4*)&A[r][c4] = *(const float4*)(src + (long)(r0 + r) * DD + c4);
    }
    __syncthreads();

    const int c  = t & 127;
    const int rh = t >> 7;                     // 0/1: rows rh*8..rh*8+7
    float acc[8];
#pragma unroll
    for (int r = 0; r < 8; ++r) acc[r] = 0.f;
#pragma unroll 4
    for (int k = 0; k < DD; ++k) {
        float wv = W[k * HH + c];
#pragma unroll
        for (int r = 0; r < 8; ++r) acc[r] += A[rh * 8 + r][k] * wv;
    }
    const float bias = bb[c];
#pragma unroll
    for (int r = 0; r < 8; ++r)
        f0[(long)(r0 + rh * 8 + r) * DD + by * HH + c] = acc[r] + bias;
}

// ---------------------------------------------------------------------------
// head v2: out[1024][64] = f0 @ Wfc + bfc; 64 blocks x 16 rows.
// 256 thr = 64 cols x 4 row-groups (4 rows each).
// ---------------------------------------------------------------------------
__global__ __launch_bounds__(256)
void head_kernel(const float* __restrict__ f0, const float* __restrict__ Wfc,
                 const float* __restrict__ bfc, float* __restrict__ out) {
    constexpr int RT = 16;
    __shared__ float aX[RT][DD];
    const int r0 = blockIdx.x * RT;
    const int t  = threadIdx.x;

#pragma unroll
    for (int i = 0; i < 4; ++i) {
        int id = i * 256 + t;
        int r = id >> 6, c4 = (id & 63) * 4;
        *(float4*)&aX[r][c4] = *(const float4*)(f0 + (long)(r0 + r) * DD + c4);
    }
    __syncthreads();

    const int c  = t & (CC - 1);
    const int rg = t >> 6;                    // 0..3 -> rows rg*4..rg*4+3
    float acc[4];
#pragma unroll
    for (int r = 0; r < 4; ++r) acc[r] = 0.f;
#pragma unroll 4
    for (int k = 0; k < DD; ++k) {
        float wv = Wfc[k * CC + c];
#pragma unroll
        for (int r = 0; r < 4; ++r) acc[r] += aX[rg * 4 + r][k] * wv;
    }
    const float bias = bfc[c];
#pragma unroll
    for (int r = 0; r < 4; ++r)
        out[(long)(r0 + rg * 4 + r) * CC + c] = acc[r] + bias;
}

// ---------------------------------------------------------------------------
extern "C" void kernel_launch(void* const* d_in, const int* in_sizes, int n_in,
                              void* d_out, int out_size, void* d_ws, size_t ws_size,
                              hipStream_t stream) {
    const int*   ids0 = (const int*)d_in[0];
    const int*   ids1 = (const int*)d_in[1];
    const int*   ids2 = (const int*)d_in[2];
    const float* feat = (const float*)d_in[3];
    const float* Wx1  = (const float*)d_in[4];
    const float* bx1  = (const float*)d_in[5];
    const float* Wn1  = (const float*)d_in[6];
    const float* bn1  = (const float*)d_in[7];
    const float* Wx2  = (const float*)d_in[8];
    const float* bx2  = (const float*)d_in[9];
    const float* Wn2  = (const float*)d_in[10];
    const float* bn2  = (const float*)d_in[11];
    const float* Wfc  = (const float*)d_in[12];
    const float* bfc  = (const float*)d_in[13];
    float* out = (float*)d_out;

    const long M1 = (long)BB * SS1;                      // 25600
    float* wsf = (float*)d_ws;
    float* g0 = wsf;  wsf += (long)BB * DD;              // 1 MB
    float* gm = wsf;  wsf += (long)BB * DD;              // 1 MB
    float* f0 = wsf;  wsf += (long)BB * DD;              // 1 MB
    unsigned short* PQb = (unsigned short*)wsf;          // 51.2 MB
    unsigned short* g1b = PQb + (long)NN * DD;           // 13.1 MB
    unsigned short* Wsw = g1b + M1 * DD;                 // 128 KB

    // 1) W prep (bf16 + B-fragment swizzle of [Wx1|Wn1])
    prep_w<<<32, 256, 0, stream>>>(Wx1, Wn1, Wsw);
    // 2) PQ = feat @ [Wx1|Wn1]  (bf16)                  [100000,256]
    pq_gemm<<<(NN + 63) / 64, 256, 0, stream>>>(feat, Wsw, PQb);
    // 3) g1 (bf16)                                      [25600,256]
    build_g1<<<M1 / 8, 256, 0, stream>>>(PQb, ids1, ids2, bx1, bn1, g1b);
    // 4) g0 (fp32)                                      [1024,256]
    build_g0<<<BB / 8, 256, 0, stream>>>(PQb, ids0, ids1, bx1, bn1, g0);
    // 5) gm = mean over S1 of g1 rows                   [1024,256]
    gm_mean<<<BB / 4, 256, 0, stream>>>(g1b, gm);
    // 6) f0 = [g0.Wx2 | gm.Wn2]  (column-split grid)    [1024,256]
    agg2<<<dim3(BB / 16, 2), 256, 0, stream>>>(g0, gm, Wx2, bx2, Wn2, bn2, f0);
    // 7) out = f0 @ Wfc + bfc                           [1024,64]
    head_kernel<<<BB / 16, 256, 0, stream>>>(f0, Wfc, bfc, out);
}